// Round 1
// baseline (1871.500 us; speedup 1.0000x reference)
//
#include <hip/hip_runtime.h>
#include <float.h>

#define VOCAB_SIZE 8192
#define DIM 64
#define NQ 32768        // 16 * 2048 queries
#define SLICES 8        // centroid slices (waves) per block
#define QPB 64          // queries per block (one per lane)

// Kernel 1: c2[c] = ||vocab[c]||^2
__global__ __launch_bounds__(256) void c2_kernel(const float* __restrict__ vocab,
                                                 float* __restrict__ c2) {
    int c = blockIdx.x * 256 + threadIdx.x;
    if (c >= VOCAB_SIZE) return;
    const float4* row = (const float4*)(vocab + (size_t)c * DIM);
    float a0 = 0.f, a1 = 0.f, a2 = 0.f, a3 = 0.f;
#pragma unroll
    for (int k = 0; k < DIM / 4; ++k) {
        float4 v = row[k];
        a0 = fmaf(v.x, v.x, a0);
        a1 = fmaf(v.y, v.y, a1);
        a2 = fmaf(v.z, v.z, a2);
        a3 = fmaf(v.w, v.w, a3);
    }
    c2[c] = (a0 + a1) + (a2 + a3);
}

// Kernel 2: per-query argmin over centroids.
// Thread layout: lane = query within block, wave = centroid slice.
// score(c) = ||c||^2 - 2 * <x, c>   (argmin-equivalent to squared distance)
__global__ __launch_bounds__(512) void argmin_kernel(const float* __restrict__ patches,
                                                     const float* __restrict__ vocab,
                                                     const float* __restrict__ c2,
                                                     int* __restrict__ out) {
    __shared__ float sbest[SLICES][QPB];
    __shared__ int   sidx[SLICES][QPB];

    const int lane = threadIdx.x & 63;
    const int s    = threadIdx.x >> 6;      // centroid slice 0..7
    const int q    = blockIdx.x * QPB + lane;

    // Load this lane's query into registers (64 floats).
    const float4* qrow = (const float4*)(patches + (size_t)q * DIM);
    float4 qv[DIM / 4];
#pragma unroll
    for (int k = 0; k < DIM / 4; ++k) qv[k] = qrow[k];

    const float4* vocab4 = (const float4*)vocab;
    float best = FLT_MAX;
    int bidx = 0;

    const int c0 = s * (VOCAB_SIZE / SLICES);
    const int c1 = c0 + (VOCAB_SIZE / SLICES);
#pragma unroll 2
    for (int c = c0; c < c1; ++c) {
        // Wave-uniform address: all 64 lanes read the same centroid row
        // -> single 16B request per load, L1-broadcast, vocab L2-resident.
        const float4* crow = vocab4 + (size_t)c * (DIM / 4);
        float c2v = c2[c];
        float a0 = 0.f, a1 = 0.f, a2 = 0.f, a3 = 0.f;
#pragma unroll
        for (int k = 0; k < DIM / 4; ++k) {
            float4 cv = crow[k];
            a0 = fmaf(qv[k].x, cv.x, a0);
            a1 = fmaf(qv[k].y, cv.y, a1);
            a2 = fmaf(qv[k].z, cv.z, a2);
            a3 = fmaf(qv[k].w, cv.w, a3);
        }
        float dot = (a0 + a1) + (a2 + a3);
        float score = fmaf(-2.0f, dot, c2v);
        // strict < keeps the FIRST (lowest-index) minimum, matching np.argmin;
        // slices are contiguous ascending c-ranges so cross-slice reduce below
        // (preferring lower s) also preserves first-index semantics.
        if (score < best) { best = score; bidx = c; }
    }

    sbest[s][lane] = best;
    sidx[s][lane]  = bidx;
    __syncthreads();

    if (threadIdx.x < QPB) {
        float b = sbest[0][lane];
        int  bi = sidx[0][lane];
#pragma unroll
        for (int ss = 1; ss < SLICES; ++ss) {
            float v  = sbest[ss][lane];
            int   vi = sidx[ss][lane];
            if (v < b) { b = v; bi = vi; }
        }
        out[blockIdx.x * QPB + lane] = bi;
    }
}

extern "C" void kernel_launch(void* const* d_in, const int* in_sizes, int n_in,
                              void* d_out, int out_size, void* d_ws, size_t ws_size,
                              hipStream_t stream) {
    const float* patches = (const float*)d_in[0];   // [16,2048,64] fp32
    const float* vocab   = (const float*)d_in[1];   // [8192,64] fp32
    float* c2 = (float*)d_ws;                       // 8192 floats scratch
    int* out  = (int*)d_out;                        // [32768] int32 tokens

    c2_kernel<<<VOCAB_SIZE / 256, 256, 0, stream>>>(vocab, c2);
    argmin_kernel<<<NQ / QPB, 512, 0, stream>>>(patches, vocab, c2, out);
}

// Round 2
// 114.381 us; speedup vs baseline: 16.3620x; 16.3620x over previous
//
#include <hip/hip_runtime.h>
#include <float.h>

#define VOCAB 8192
#define DIM 64
#define NQ 32768
#define NSLICE 4
#define CSLICE (VOCAB / NSLICE)     // 2048 centroids per slice
#define CHUNK 64                    // centroids staged per LDS buffer
#define NCHUNK (CSLICE / CHUNK)     // 32
#define THREADS 256

typedef __attribute__((ext_vector_type(8))) _Float16 half8;
typedef __attribute__((ext_vector_type(4))) float f32x4;

#define LO_SCALE 4096.0f
#define LO_INV   2.44140625e-4f     // 1/4096

// ---------------- c2[c] = ||vocab[c]||^2 (fp32, same as round 1) ----------------
__global__ __launch_bounds__(256) void c2_kernel(const float* __restrict__ vocab,
                                                 float* __restrict__ c2) {
    int c = blockIdx.x * 256 + threadIdx.x;
    const float4* row = (const float4*)(vocab + (size_t)c * DIM);
    float a0 = 0.f, a1 = 0.f, a2 = 0.f, a3 = 0.f;
#pragma unroll
    for (int k = 0; k < DIM / 4; ++k) {
        float4 v = row[k];
        a0 = fmaf(v.x, v.x, a0); a1 = fmaf(v.y, v.y, a1);
        a2 = fmaf(v.z, v.z, a2); a3 = fmaf(v.w, v.w, a3);
    }
    c2[c] = (a0 + a1) + (a2 + a3);
}

// ---------------- split fp32 -> f16 hi + f16 lo*4096 ----------------
__global__ __launch_bounds__(256) void split_kernel(const float* __restrict__ src,
                                                    _Float16* __restrict__ hi,
                                                    _Float16* __restrict__ lo) {
    int t = blockIdx.x * 256 + threadIdx.x;     // one thread per 8 elements
    const float4* s = (const float4*)(src + (size_t)t * 8);
    float4 f0 = s[0], f1 = s[1];
    float x[8] = {f0.x, f0.y, f0.z, f0.w, f1.x, f1.y, f1.z, f1.w};
    half8 h, l;
#pragma unroll
    for (int j = 0; j < 8; ++j) {
        _Float16 hh = (_Float16)x[j];
        h[j] = hh;
        l[j] = (_Float16)((x[j] - (float)hh) * LO_SCALE);   // scaled lo: stays normal
    }
    *(half8*)(hi + (size_t)t * 8) = h;
    *(half8*)(lo + (size_t)t * 8) = l;
}

// async global->LDS, 16B per lane, LDS dest = uniform base + lane*16 (implicit)
__device__ __forceinline__ void gload_lds(const _Float16* g, void* lds_dst) {
    __builtin_amdgcn_global_load_lds(
        (const __attribute__((address_space(1))) void*)g,
        (__attribute__((address_space(3))) void*)lds_dst, 16, 0, 0);
}

// ---------------- main: MFMA GEMM + fused argmin ----------------
// A = patches (M=queries), B = vocab (N=centroids), mfma_f32_16x16x32_f16.
// A frag: lane holds row (lane&15), k = (lane>>4)*8+e.  B frag: col (lane&15),
// k = (lane>>4)*8+e.  C: col = lane&15 (centroid), row = (lane>>4)*4+reg (query).
// LDS tile [64 rows][8 x 16B], XOR-swizzled: linear pos (row,c) holds source
// (row, c ^ (row&7)); swizzle applied on the global SOURCE address at staging
// (m173 pattern) and on the ds_read address (T2).
__global__ __launch_bounds__(THREADS, 2)
void argmin_mfma(const float* __restrict__ patches,
                 const _Float16* __restrict__ vhi,
                 const _Float16* __restrict__ vlo,
                 const float* __restrict__ c2g,
                 float* __restrict__ ws_best,
                 int*   __restrict__ ws_idx) {
    __shared__ __align__(16) char smem[2 * 16384];   // [buf][hi 8KB | lo 8KB]

    const int tid   = threadIdx.x;
    const int lane  = tid & 63;
    const int w     = tid >> 6;                 // wave 0..3
    const int slice = blockIdx.x & (NSLICE - 1);
    const int qg    = blockIdx.x >> 2;          // 0..127
    const int qbase = qg * 256 + w * 64;        // this wave's 64 queries
    const int cbase = slice * CSLICE;

    // ---- load + split this wave's A fragments (queries) into registers ----
    const int arow = lane & 15;                 // query row within 16-tile
    const int akc  = lane >> 4;                 // k-chunk 0..3 (8 elems each)
    half8 Ah[4][2], Al[4][2];
#pragma unroll
    for (int t = 0; t < 4; ++t)
#pragma unroll
        for (int ks = 0; ks < 2; ++ks) {
            const float* p = patches + (size_t)(qbase + t * 16 + arow) * DIM
                           + ks * 32 + akc * 8;
            float4 f0 = *(const float4*)p;
            float4 f1 = *(const float4*)(p + 4);
            float x[8] = {f0.x, f0.y, f0.z, f0.w, f1.x, f1.y, f1.z, f1.w};
            half8 h, l;
#pragma unroll
            for (int j = 0; j < 8; ++j) {
                _Float16 hh = (_Float16)x[j];
                h[j] = hh;
                l[j] = (_Float16)((x[j] - (float)hh) * LO_SCALE);
            }
            Ah[t][ks] = h; Al[t][ks] = l;
        }

    // staging source offset (elems): row = r0 + (lane>>3), col16' = (lane&7)^(lane>>3)
    const int s_srcoff = ((lane >> 3) * DIM) + (((lane & 7) ^ (lane >> 3)) * 8);
    // frag ds_read byte offsets within a region: row fr, swizzled k-chunk
    const int fr = lane & 15;
    const int fx = fr & 7;
    const int b_off0 = fr * 128 + (((0 * 4 + akc) ^ fx) * 16);   // kstep 0
    const int b_off1 = fr * 128 + (((1 * 4 + akc) ^ fx) * 16);   // kstep 1

    float best[4][4];
    int   bidx[4][4];
#pragma unroll
    for (int t = 0; t < 4; ++t)
#pragma unroll
        for (int j = 0; j < 4; ++j) { best[t][j] = FLT_MAX; bidx[t][j] = 0; }

    // ---- stage chunk 0 ----
    {
        const size_t crow = (size_t)cbase * DIM;
#pragma unroll
        for (int j = 0; j < 2; ++j) {
            int r0 = (w + 4 * j) * 8;           // 8 rows = 1KB per instr
            gload_lds(vhi + crow + (size_t)r0 * DIM + s_srcoff, smem + r0 * 128);
            gload_lds(vlo + crow + (size_t)r0 * DIM + s_srcoff, smem + 8192 + r0 * 128);
        }
    }
    __syncthreads();

    for (int ch = 0; ch < NCHUNK; ++ch) {
        const int cur = ch & 1;
        if (ch + 1 < NCHUNK) {                  // prefetch next chunk into other buffer
            const size_t crow = (size_t)(cbase + (ch + 1) * CHUNK) * DIM;
            char* dst = smem + (cur ^ 1) * 16384;
#pragma unroll
            for (int j = 0; j < 2; ++j) {
                int r0 = (w + 4 * j) * 8;
                gload_lds(vhi + crow + (size_t)r0 * DIM + s_srcoff, dst + r0 * 128);
                gload_lds(vlo + crow + (size_t)r0 * DIM + s_srcoff, dst + 8192 + r0 * 128);
            }
        }
        const char* hib = smem + cur * 16384;
        const char* lob = hib + 8192;
        const int cb = cbase + ch * CHUNK;

#pragma unroll
        for (int nt = 0; nt < 4; ++nt) {
            const int rt = nt * 16;
            half8 Bh0 = *(const half8*)(hib + rt * 128 + b_off0);
            half8 Bh1 = *(const half8*)(hib + rt * 128 + b_off1);
            half8 Bl0 = *(const half8*)(lob + rt * 128 + b_off0);
            half8 Bl1 = *(const half8*)(lob + rt * 128 + b_off1);
            const float c2v = c2g[cb + rt + fr];    // this lane's centroid col
            const int  cidx = cb + rt + fr;
#pragma unroll
            for (int t = 0; t < 4; ++t) {
                f32x4 am = {0.f, 0.f, 0.f, 0.f};    // hi*hi
                f32x4 al = {0.f, 0.f, 0.f, 0.f};    // cross terms, scale 4096
                am = __builtin_amdgcn_mfma_f32_16x16x32_f16(Ah[t][0], Bh0, am, 0, 0, 0);
                am = __builtin_amdgcn_mfma_f32_16x16x32_f16(Ah[t][1], Bh1, am, 0, 0, 0);
                al = __builtin_amdgcn_mfma_f32_16x16x32_f16(Ah[t][0], Bl0, al, 0, 0, 0);
                al = __builtin_amdgcn_mfma_f32_16x16x32_f16(Ah[t][1], Bl1, al, 0, 0, 0);
                al = __builtin_amdgcn_mfma_f32_16x16x32_f16(Al[t][0], Bh0, al, 0, 0, 0);
                al = __builtin_amdgcn_mfma_f32_16x16x32_f16(Al[t][1], Bh1, al, 0, 0, 0);
#pragma unroll
                for (int j = 0; j < 4; ++j) {
                    float dot = fmaf(al[j], LO_INV, am[j]);
                    float s   = fmaf(-2.0f, dot, c2v);
                    if (s < best[t][j]) { best[t][j] = s; bidx[t][j] = cidx; }
                }
            }
        }
        __syncthreads();    // drains prefetch (vmcnt0) + guards buffer reuse
    }

    // ---- butterfly argmin-merge across the 16 column-lanes of each row-group ----
#pragma unroll
    for (int t = 0; t < 4; ++t)
#pragma unroll
        for (int j = 0; j < 4; ++j) {
            float b = best[t][j]; int bi = bidx[t][j];
#pragma unroll
            for (int d = 1; d < 16; d <<= 1) {
                float ob = __shfl_xor(b, d, 64);
                int   oi = __shfl_xor(bi, d, 64);
                if (ob < b || (ob == b && oi < bi)) { b = ob; bi = oi; }  // first-index ties
            }
            best[t][j] = b; bidx[t][j] = bi;
        }

    if ((lane & 15) == 0) {
        const int rg = lane >> 4;
#pragma unroll
        for (int t = 0; t < 4; ++t)
#pragma unroll
            for (int j = 0; j < 4; ++j) {
                int q = qbase + t * 16 + rg * 4 + j;
                ws_best[(size_t)slice * NQ + q] = best[t][j];
                ws_idx [(size_t)slice * NQ + q] = bidx[t][j];
            }
    }
}

// ---------------- merge slices ----------------
__global__ __launch_bounds__(256) void merge_kernel(const float* __restrict__ ws_best,
                                                    const int* __restrict__ ws_idx,
                                                    int* __restrict__ out) {
    int q = blockIdx.x * 256 + threadIdx.x;
    float b = ws_best[q]; int bi = ws_idx[q];
#pragma unroll
    for (int s = 1; s < NSLICE; ++s) {
        float v = ws_best[(size_t)s * NQ + q];
        int  vi = ws_idx[(size_t)s * NQ + q];
        if (v < b || (v == b && vi < bi)) { b = v; bi = vi; }
    }
    out[q] = bi;
}

extern "C" void kernel_launch(void* const* d_in, const int* in_sizes, int n_in,
                              void* d_out, int out_size, void* d_ws, size_t ws_size,
                              hipStream_t stream) {
    const float* patches = (const float*)d_in[0];   // [32768][64] fp32
    const float* vocab   = (const float*)d_in[1];   // [8192][64] fp32
    char* ws = (char*)d_ws;
    float*    c2    = (float*)ws;                                   // 32 KB
    _Float16* vhi   = (_Float16*)(ws + 32768);                      // 1 MB
    _Float16* vlo   = (_Float16*)(ws + 32768 + 1048576);            // 1 MB
    float*    wbest = (float*)(ws + 32768 + 2097152);               // 512 KB
    int*      widx  = (int*)  (ws + 32768 + 2097152 + 524288);      // 512 KB
    int* out = (int*)d_out;

    c2_kernel   <<<VOCAB / 256, 256, 0, stream>>>(vocab, c2);
    split_kernel<<<(VOCAB * DIM / 8) / 256, 256, 0, stream>>>(vocab, vhi, vlo);
    argmin_mfma <<<128 * NSLICE, THREADS, 0, stream>>>(patches, vhi, vlo, c2, wbest, widx);
    merge_kernel<<<NQ / 256, 256, 0, stream>>>(wbest, widx, out);
}